// Round 1
// 879.517 us; speedup vs baseline: 1.2432x; 1.2432x over previous
//
#include <hip/hip_runtime.h>

typedef __attribute__((ext_vector_type(8))) short short8;
typedef __attribute__((ext_vector_type(4))) float floatx4;
typedef __attribute__((ext_vector_type(4))) int intx4;

#define NTOK 256
#define NCH 18                 // K chunks of 32: 16 emb + 2 tail
#define BCHUNK 16384           // bytes per packed-B chunk: [4 q][256 col][8] bf16
#define WPK_BYTES (NCH * BCHUNK)

__device__ __forceinline__ unsigned short f2bf(float f) {
    unsigned u = __builtin_bit_cast(unsigned, f);
    u += 0x7FFFu + ((u >> 16) & 1u);   // round-to-nearest-even
    return (unsigned short)(u >> 16);
}

__device__ __forceinline__ short8 cvt_frag(floatx4 x0, floatx4 x1) {
    short8 v;
    v[0] = (short)f2bf(x0[0]); v[1] = (short)f2bf(x0[1]);
    v[2] = (short)f2bf(x0[2]); v[3] = (short)f2bf(x0[3]);
    v[4] = (short)f2bf(x1[0]); v[5] = (short)f2bf(x1[1]);
    v[6] = (short)f2bf(x1[2]); v[7] = (short)f2bf(x1[3]);
    return v;
}

// Pack weights gload_lds-ready: Wpk[ch][q][col][j] = Wcat[k=ch*32+q*8+j][col] (bf16).
// One thread per (ch,q,col): writes 16B coalesced, reads col-coalesced.
__global__ void prep_kernel(const float* __restrict__ app_W,
                            const float* __restrict__ app_b,
                            const float* __restrict__ st_W,
                            const float* __restrict__ st_b,
                            unsigned short* __restrict__ Wpk,
                            float* __restrict__ bias) {
    const int col = threadIdx.x;                 // 0..255
    const int ch = blockIdx.x >> 2, q = blockIdx.x & 3;
    short8 v;
    #pragma unroll
    for (int j = 0; j < 8; ++j) {
        const int k = ch * 32 + q * 8 + j;
        float f;
        if (k < 513)      f = app_W[(size_t)k * NTOK + col];
        else if (k < 568) f = st_W[(size_t)(k - 513) * NTOK + col];
        else              f = 0.0f;
        v[j] = (short)f2bf(f);
    }
    ((short8*)Wpk)[(size_t)blockIdx.x * NTOK + col] = v;
    if (blockIdx.x == 0) bias[col] = app_b[col] + st_b[col];
}

__device__ __forceinline__ float load_tail(const float* __restrict__ vis,
                                           const float* __restrict__ bbox,
                                           const float* __restrict__ kp,
                                           int token, int k) {
    float v = 0.0f;
    if (k < 568) {
        const float* base = (k < 513) ? vis : ((k < 517) ? bbox : kp);
        int off = (k < 513) ? token
                 : ((k < 517) ? (token * 4 + (k - 513))
                              : (token * 51 + (k - 517)));
        v = base[off];
    }
    return v;
}

__device__ __forceinline__ void gload16(const void* g, void* l) {
    __builtin_amdgcn_global_load_lds(
        (const __attribute__((address_space(1))) void*)g,
        (__attribute__((address_space(3))) void*)l, 16, 0, 0);
}

// Block: 128 rows x 256 cols, 512 threads (8 waves, 2x4 -> wave tile 64x64).
// A+B DMA-staged to LDS double buffer; counted vmcnt(4); 2 barriers/iter.
__global__ __launch_bounds__(512, 2)
void gemm_kernel(const float* __restrict__ emb, const float* __restrict__ vis,
                 const float* __restrict__ bbox, const float* __restrict__ kp,
                 const int* __restrict__ mask,
                 const unsigned short* __restrict__ Wpk,
                 const float* __restrict__ bias,
                 float* __restrict__ out) {
    // A: [buf][row 0..127][32 f32]; phys 16B-slot ps holds logical slot ps^(row&7)
    __shared__ float As[2][128][32];               // 32 KB
    // B: [buf][q][col][8 bf16] — exactly the Wpk chunk layout, staged linearly
    __shared__ unsigned short Bs[2][4][256][8];    // 32 KB

    const int t    = threadIdx.x;
    const int lane = t & 63;
    const int w    = t >> 6;            // wave 0..7
    const int q    = lane >> 4;         // quad 0..3
    const int l16  = lane & 15;
    const int wrow = (w >> 2) * 64;     // row offset within block (0 / 64)
    const int col0 = (w & 3) * 64;      // col offset (0/64/128/192)
    const int row0 = blockIdx.x * 128;

    // ---- staging addresses ----
    // A instr i: LDS bytes i*8192 + t*16  <->  row = i*64 + (t>>3), phys slot = t&7
    // source slot pre-swizzled so that swizzled ds_read gets logical data
    const int srow  = t >> 3;                       // 0..63
    const int sslot = (t & 7) ^ (srow & 7);         // logical 16B slot at source
    const float* aS0 = emb + (size_t)(row0 + srow) * 512 + sslot * 4;
    const float* aS1 = aS0 + (size_t)64 * 512;      // rows +64 (same swizzle: 64%8==0)
    const char*  bS  = (const char*)Wpk + (size_t)t * 16;  // + ch*BCHUNK (+8192 for instr 1)
    char* aD = (char*)(&As[0][0][0]) + w * 1024;    // wave-uniform LDS bases
    char* bD = (char*)(&Bs[0][0][0][0]) + w * 1024;

#define STAGE(c, buf) do {                                              \
        gload16(aS0 + (c) * 32,                 aD + (buf) * 16384);    \
        gload16(aS1 + (c) * 32,                 aD + (buf) * 16384 + 8192); \
        gload16(bS + (size_t)(c) * BCHUNK,        bD + (buf) * 16384);    \
        gload16(bS + (size_t)(c) * BCHUNK + 8192, bD + (buf) * 16384 + 8192); \
    } while (0)

    floatx4 acc[4][4] = {};   // 64 regs (unified VGPR/AGPR)

    // ---- issue chunk-0 DMA first: lands while we do the tail gather ----
    STAGE(0, 0);

    // ---- tail chunks 16..17 (vis/bbox/kp gather) computed FIRST so their
    //      compiler-managed loads are fully drained before the counted loop ----
    #pragma unroll
    for (int ch = 16; ch < 18; ++ch) {
        short8 b2[4];
        #pragma unroll
        for (int ct = 0; ct < 4; ++ct)
            b2[ct] = *(const short8*)((const char*)Wpk + (size_t)ch * BCHUNK +
                                      q * 4096 + (size_t)(col0 + ct * 16 + l16) * 16);
        const int kb = ch * 32 + q * 8;
        #pragma unroll
        for (int rt = 0; rt < 4; ++rt) {
            const int token = row0 + wrow + rt * 16 + l16;
            short8 a;
            #pragma unroll
            for (int j = 0; j < 8; ++j)
                a[j] = (short)f2bf(load_tail(vis, bbox, kp, token, kb + j));
            #pragma unroll
            for (int ct = 0; ct < 4; ++ct)
                acc[rt][ct] = __builtin_amdgcn_mfma_f32_16x16x32_bf16(
                    a, b2[ct], acc[rt][ct], 0, 0, 0);
        }
    }

    __builtin_amdgcn_sched_barrier(0);   // keep gather loads out of the counted loop

    // ---- main pipelined loop: chunks 0..15, 1-chunk-ahead DMA, vmcnt never 0
    //      until the last iteration ----
    #pragma unroll
    for (int ch = 0; ch < 16; ++ch) {
        const int cur = ch & 1;
        if (ch < 15) {
            STAGE(ch + 1, cur ^ 1);
            asm volatile("s_waitcnt vmcnt(4)" ::: "memory");  // chunk ch landed
        } else {
            asm volatile("s_waitcnt vmcnt(0)" ::: "memory");
        }
        __builtin_amdgcn_s_barrier();          // all waves' shares landed
        __builtin_amdgcn_sched_barrier(0);     // pin reads below the barrier

        short8 bfr[4];
        #pragma unroll
        for (int ct = 0; ct < 4; ++ct)
            bfr[ct] = *(const short8*)&Bs[cur][q][col0 + ct * 16 + l16][0];
        short8 afr[4];
        #pragma unroll
        for (int rt = 0; rt < 4; ++rt) {
            const int r = wrow + rt * 16 + l16;
            const floatx4 x0 = *(const floatx4*)&As[cur][r][((2 * q) ^ (r & 7)) * 4];
            const floatx4 x1 = *(const floatx4*)&As[cur][r][((2 * q + 1) ^ (r & 7)) * 4];
            afr[rt] = cvt_frag(x0, x1);
        }
        #pragma unroll
        for (int rt = 0; rt < 4; ++rt)
            #pragma unroll
            for (int ct = 0; ct < 4; ++ct)
                acc[rt][ct] = __builtin_amdgcn_mfma_f32_16x16x32_bf16(
                    afr[rt], bfr[ct], acc[rt][ct], 0, 0, 0);

        __builtin_amdgcn_sched_barrier(0);     // reads consumed before re-stage
        __builtin_amdgcn_s_barrier();          // protect buf from next DMA
    }
#undef STAGE

    // ---- epilogue: C/D layout col = l16, row = q*4 + reg ----
    float bv[4];
    #pragma unroll
    for (int ct = 0; ct < 4; ++ct) bv[ct] = bias[col0 + ct * 16 + l16];

    #pragma unroll
    for (int rt = 0; rt < 4; ++rt) {
        const int rbase = row0 + wrow + rt * 16 + q * 4;
        const intx4 mv = *(const intx4*)(mask + rbase);
        #pragma unroll
        for (int reg = 0; reg < 4; ++reg) {
            const float msc = mv[reg] ? 1.0f : 0.0f;
            #pragma unroll
            for (int ct = 0; ct < 4; ++ct)
                out[(size_t)(rbase + reg) * NTOK + col0 + ct * 16 + l16] =
                    (acc[rt][ct][reg] + bv[ct]) * msc;
        }
    }
}

extern "C" void kernel_launch(void* const* d_in, const int* in_sizes, int n_in,
                              void* d_out, int out_size, void* d_ws, size_t ws_size,
                              hipStream_t stream) {
    const float* emb   = (const float*)d_in[0];
    const float* vis   = (const float*)d_in[1];
    const float* bbox  = (const float*)d_in[2];
    const float* kp    = (const float*)d_in[3];
    const int*   mask  = (const int*)d_in[4];
    const float* app_W = (const float*)d_in[5];
    const float* app_b = (const float*)d_in[6];
    const float* st_W  = (const float*)d_in[7];
    const float* st_b  = (const float*)d_in[8];

    unsigned short* Wpk = (unsigned short*)d_ws;
    float* bias = (float*)((char*)d_ws + WPK_BYTES);
    float* out = (float*)d_out;

    hipLaunchKernelGGL(prep_kernel, dim3(NCH * 4), dim3(NTOK), 0, stream,
                       app_W, app_b, st_W, st_b, Wpk, bias);
    hipLaunchKernelGGL(gemm_kernel, dim3(2048), dim3(512), 0, stream,
                       emb, vis, bbox, kp, mask, Wpk, bias, out);
}

// Round 2
// 865.516 us; speedup vs baseline: 1.2633x; 1.0162x over previous
//
#include <hip/hip_runtime.h>

typedef __attribute__((ext_vector_type(8))) short short8;
typedef __attribute__((ext_vector_type(4))) float floatx4;
typedef __attribute__((ext_vector_type(4))) int intx4;

#define NTOK 256
#define NCH 18                 // K chunks of 32: 16 emb + 2 tail
#define BCHUNK 16384           // bytes per packed-B chunk: [4 q][256 col][8] bf16
#define WPK_BYTES (NCH * BCHUNK)

__device__ __forceinline__ unsigned short f2bf(float f) {
    unsigned u = __builtin_bit_cast(unsigned, f);
    u += 0x7FFFu + ((u >> 16) & 1u);   // round-to-nearest-even
    return (unsigned short)(u >> 16);
}

__device__ __forceinline__ short8 cvt_frag(floatx4 x0, floatx4 x1) {
    short8 v;
    v[0] = (short)f2bf(x0[0]); v[1] = (short)f2bf(x0[1]);
    v[2] = (short)f2bf(x0[2]); v[3] = (short)f2bf(x0[3]);
    v[4] = (short)f2bf(x1[0]); v[5] = (short)f2bf(x1[1]);
    v[6] = (short)f2bf(x1[2]); v[7] = (short)f2bf(x1[3]);
    return v;
}

// Pack weights gload_lds-ready: Wpk[ch][q][col][j] = Wcat[k=ch*32+q*8+j][col] (bf16).
__global__ void prep_kernel(const float* __restrict__ app_W,
                            const float* __restrict__ app_b,
                            const float* __restrict__ st_W,
                            const float* __restrict__ st_b,
                            unsigned short* __restrict__ Wpk,
                            float* __restrict__ bias) {
    const int col = threadIdx.x;                 // 0..255
    const int ch = blockIdx.x >> 2, q = blockIdx.x & 3;
    short8 v;
    #pragma unroll
    for (int j = 0; j < 8; ++j) {
        const int k = ch * 32 + q * 8 + j;
        float f;
        if (k < 513)      f = app_W[(size_t)k * NTOK + col];
        else if (k < 568) f = st_W[(size_t)(k - 513) * NTOK + col];
        else              f = 0.0f;
        v[j] = (short)f2bf(f);
    }
    ((short8*)Wpk)[(size_t)blockIdx.x * NTOK + col] = v;
    if (blockIdx.x == 0) bias[col] = app_b[col] + st_b[col];
}

__device__ __forceinline__ float load_tail(const float* __restrict__ vis,
                                           const float* __restrict__ bbox,
                                           const float* __restrict__ kp,
                                           int token, int k) {
    float v = 0.0f;
    if (k < 568) {
        const float* base = (k < 513) ? vis : ((k < 517) ? bbox : kp);
        int off = (k < 513) ? token
                 : ((k < 517) ? (token * 4 + (k - 513))
                              : (token * 51 + (k - 517)));
        v = base[off];
    }
    return v;
}

__device__ __forceinline__ void gload16(const void* g, void* l) {
    __builtin_amdgcn_global_load_lds(
        (const __attribute__((address_space(1))) void*)g,
        (__attribute__((address_space(3))) void*)l, 16, 0, 0);
}

// Block: 128 rows x 256 cols, 512 threads (8 waves, 2x4 -> wave tile 64x64).
// 4-buffer LDS pipeline, depth-2 DMA lookahead, vmcnt(8), ONE barrier/iter.
__global__ __launch_bounds__(512, 2)
void gemm_kernel(const float* __restrict__ emb, const float* __restrict__ vis,
                 const float* __restrict__ bbox, const float* __restrict__ kp,
                 const int* __restrict__ mask,
                 const unsigned short* __restrict__ Wpk,
                 const float* __restrict__ bias,
                 float* __restrict__ out) {
    // A: [buf][row 0..127][32 f32]; phys 16B-slot ps holds logical slot ps^(row&7)
    __shared__ float As[4][128][32];               // 64 KB
    // B: [buf][q][col][8 bf16] — exactly the Wpk chunk layout, staged linearly
    __shared__ unsigned short Bs[4][4][256][8];    // 64 KB

    const int t    = threadIdx.x;
    const int lane = t & 63;
    const int w    = t >> 6;            // wave 0..7
    const int q    = lane >> 4;         // quad 0..3
    const int l16  = lane & 15;
    const int wrow = (w >> 2) * 64;     // row offset within block (0 / 64)
    const int col0 = (w & 3) * 64;      // col offset (0/64/128/192)
    const int row0 = blockIdx.x * 128;

    // ---- staging addresses ----
    // A instr i: LDS bytes i*8192 + t*16  <->  row = i*64 + (t>>3), phys slot = t&7
    // source slot pre-swizzled so that swizzled ds_read gets logical data
    const int srow  = t >> 3;                       // 0..63
    const int sslot = (t & 7) ^ (srow & 7);         // logical 16B slot at source
    const float* aS0 = emb + (size_t)(row0 + srow) * 512 + sslot * 4;
    const float* aS1 = aS0 + (size_t)64 * 512;      // rows +64 (same swizzle: 64%8==0)
    const char*  bS  = (const char*)Wpk + (size_t)t * 16;
    char* aD = (char*)(&As[0][0][0]) + w * 1024;    // wave-uniform LDS bases
    char* bD = (char*)(&Bs[0][0][0][0]) + w * 1024;

#define STAGE(c, buf) do {                                              \
        gload16(aS0 + (c) * 32,                 aD + (buf) * 16384);    \
        gload16(aS1 + (c) * 32,                 aD + (buf) * 16384 + 8192); \
        gload16(bS + (size_t)(c) * BCHUNK,        bD + (buf) * 16384);    \
        gload16(bS + (size_t)(c) * BCHUNK + 8192, bD + (buf) * 16384 + 8192); \
    } while (0)

    floatx4 acc[4][4] = {};   // 64 regs (unified VGPR/AGPR)

    // ---- issue chunks 0 and 1 DMA first: land while we do the tail gather ----
    STAGE(0, 0);
    STAGE(1, 1);

    // ---- tail chunks 16..17 (vis/bbox/kp gather) computed FIRST: all their
    //      compiler-managed loads are register-consumed (hence vmcnt-retired)
    //      before the counted loop starts ----
    #pragma unroll
    for (int ch = 16; ch < 18; ++ch) {
        short8 b2[4];
        #pragma unroll
        for (int ct = 0; ct < 4; ++ct)
            b2[ct] = *(const short8*)((const char*)Wpk + (size_t)ch * BCHUNK +
                                      q * 4096 + (size_t)(col0 + ct * 16 + l16) * 16);
        const int kb = ch * 32 + q * 8;
        #pragma unroll
        for (int rt = 0; rt < 4; ++rt) {
            const int token = row0 + wrow + rt * 16 + l16;
            short8 a;
            #pragma unroll
            for (int j = 0; j < 8; ++j)
                a[j] = (short)f2bf(load_tail(vis, bbox, kp, token, kb + j));
            #pragma unroll
            for (int ct = 0; ct < 4; ++ct)
                acc[rt][ct] = __builtin_amdgcn_mfma_f32_16x16x32_bf16(
                    a, b2[ct], acc[rt][ct], 0, 0, 0);
        }
    }

    __builtin_amdgcn_sched_barrier(0);   // keep gather loads out of the counted loop

    // ---- main loop, chunks 0..15: issue ch+2, wait oldest (3 in flight),
    //      single barrier per iteration (4 buffers make reuse barrier-safe:
    //      DMA@iter ch into buf[(ch+2)&3] is ordered after BAR(ch-1), which all
    //      waves' reads of that buf (iter ch-2) precede) ----
    #pragma unroll
    for (int ch = 0; ch < 16; ++ch) {
        const int cur = ch & 3;
        if (ch < 14) {
            STAGE(ch + 2, (ch + 2) & 3);
            asm volatile("s_waitcnt vmcnt(8)" ::: "memory");  // chunk ch landed
        } else if (ch == 14) {
            asm volatile("s_waitcnt vmcnt(4)" ::: "memory");  // chunk 14 landed
        } else {
            asm volatile("s_waitcnt vmcnt(0)" ::: "memory");  // chunk 15 landed
        }
        __builtin_amdgcn_s_barrier();          // all waves' shares landed
        __builtin_amdgcn_sched_barrier(0);     // pin reads below the barrier

        short8 bfr[4];
        #pragma unroll
        for (int ct = 0; ct < 4; ++ct)
            bfr[ct] = *(const short8*)&Bs[cur][q][col0 + ct * 16 + l16][0];
        short8 afr[4];
        #pragma unroll
        for (int rt = 0; rt < 4; ++rt) {
            const int r = wrow + rt * 16 + l16;
            const floatx4 x0 = *(const floatx4*)&As[cur][r][((2 * q) ^ (r & 7)) * 4];
            const floatx4 x1 = *(const floatx4*)&As[cur][r][((2 * q + 1) ^ (r & 7)) * 4];
            afr[rt] = cvt_frag(x0, x1);
        }
        #pragma unroll
        for (int rt = 0; rt < 4; ++rt)
            #pragma unroll
            for (int ct = 0; ct < 4; ++ct)
                acc[rt][ct] = __builtin_amdgcn_mfma_f32_16x16x32_bf16(
                    afr[rt], bfr[ct], acc[rt][ct], 0, 0, 0);
    }
#undef STAGE

    // ---- epilogue: C/D layout col = l16, row = q*4 + reg ----
    float bv[4];
    #pragma unroll
    for (int ct = 0; ct < 4; ++ct) bv[ct] = bias[col0 + ct * 16 + l16];

    #pragma unroll
    for (int rt = 0; rt < 4; ++rt) {
        const int rbase = row0 + wrow + rt * 16 + q * 4;
        const intx4 mv = *(const intx4*)(mask + rbase);
        #pragma unroll
        for (int reg = 0; reg < 4; ++reg) {
            const float msc = mv[reg] ? 1.0f : 0.0f;
            #pragma unroll
            for (int ct = 0; ct < 4; ++ct)
                out[(size_t)(rbase + reg) * NTOK + col0 + ct * 16 + l16] =
                    (acc[rt][ct][reg] + bv[ct]) * msc;
        }
    }
}

extern "C" void kernel_launch(void* const* d_in, const int* in_sizes, int n_in,
                              void* d_out, int out_size, void* d_ws, size_t ws_size,
                              hipStream_t stream) {
    const float* emb   = (const float*)d_in[0];
    const float* vis   = (const float*)d_in[1];
    const float* bbox  = (const float*)d_in[2];
    const float* kp    = (const float*)d_in[3];
    const int*   mask  = (const int*)d_in[4];
    const float* app_W = (const float*)d_in[5];
    const float* app_b = (const float*)d_in[6];
    const float* st_W  = (const float*)d_in[7];
    const float* st_b  = (const float*)d_in[8];

    unsigned short* Wpk = (unsigned short*)d_ws;
    float* bias = (float*)((char*)d_ws + WPK_BYTES);
    float* out = (float*)d_out;

    hipLaunchKernelGGL(prep_kernel, dim3(NCH * 4), dim3(NTOK), 0, stream,
                       app_W, app_b, st_W, st_b, Wpk, bias);
    hipLaunchKernelGGL(gemm_kernel, dim3(2048), dim3(512), 0, stream,
                       emb, vis, bbox, kp, mask, Wpk, bias, out);
}